// Round 7
// baseline (349.362 us; speedup 1.0000x reference)
//
#include <hip/hip_runtime.h>
#include <hip/hip_bf16.h>
#include <stdint.h>

#define B_   2048
#define P_   20
#define D_   64
#define V_   100000
#define T_   33
#define FIN  2240          // 35*64
#define KE   2112          // 33*64  (emb-only K; raw cols folded into epilogue)
#define M_   (B_*P_)       // 40960
#define H1_  512
#define H2_  256
#define NKT  33            // K-tiles of 64

using bf16 = __hip_bfloat16;
typedef __bf16 bf16x8 __attribute__((ext_vector_type(8)));
typedef float  f32x4  __attribute__((ext_vector_type(4)));

__device__ __forceinline__ void gload16(const void* g, void* l) {
    __builtin_amdgcn_global_load_lds(
        (const __attribute__((address_space(1))) uint32_t*)g,
        (__attribute__((address_space(3))) uint32_t*)l, 16, 0, 0);
}
__device__ __forceinline__ void gload4(const void* g, void* l) {
    __builtin_amdgcn_global_load_lds(
        (const __attribute__((address_space(1))) uint32_t*)g,
        (__attribute__((address_space(3))) uint32_t*)l, 4, 0, 0);
}
__device__ __forceinline__ unsigned short b16bits(float f) {
    return __builtin_bit_cast(unsigned short, __float2bfloat16(f));
}

// LDS map (bytes).  Main loop:           Epilogue (reuses freed space):
//   Als  [0, 81920)                        Ach0 [0,20480) Ach1 [20480,40960)
//   Bls  [81920, 147456)                   Bch0 [40960,73728) Bch1 [73728,106496)
//   ring [147456, 148736)                  tables/logq/logits [106496,119168)
#define OFF_BLS   81920
#define OFF_RING  147456
#define OFF_ACH   0
#define OFF_BCH   40960
#define OFF_W3S   106496
#define OFF_B2S   107520
#define OFF_B1S   108544
#define OFF_S0S   110592
#define OFF_S1S   112640
#define OFF_XRS   114688
#define OFF_LOGQ  115968
#define OFF_LOG   118528
#define LDS_BYTES 148736

// ---------------------------------------------------------------------------
// prep 1: column sums of W1 rows 0..63 (S0) and 64..127 (S1).  S01 = [S0|S1]
// ---------------------------------------------------------------------------
__global__ __launch_bounds__(256) void colsum_k(
    const float* __restrict__ W1, float* __restrict__ S01)
{
    int g = blockIdx.x * 256 + threadIdx.x;   // 0..1023
    int s = g >> 9, n = g & 511;
    const float* p = W1 + (size_t)(s * 64) * H1_ + n;
    float acc = 0.f;
    #pragma unroll 8
    for (int k = 0; k < 64; ++k) acc += p[(size_t)k * H1_];
    S01[s * H1_ + n] = acc;
}

// ---------------------------------------------------------------------------
// prep 2: W1 rows 128.. -> W1t (512 x 2112) bf16 row-major (transposed)
// ---------------------------------------------------------------------------
__global__ __launch_bounds__(256) void w1t_k(
    const float* __restrict__ W1, bf16* __restrict__ W1t)
{
    int idx = blockIdx.x * 256 + threadIdx.x;   // n*KE + k
    int n = idx / KE;
    int k = idx - n * KE;
    W1t[idx] = __float2bfloat16(W1[(size_t)(k + 128) * H1_ + n]);
}

// ---------------------------------------------------------------------------
// prep 3: generic W (K x N fp32) -> Wt (N x K bf16)
// ---------------------------------------------------------------------------
__global__ __launch_bounds__(256) void transpose_bf16_k(
    const float* __restrict__ W, bf16* __restrict__ Wt, int K, int N)
{
    int idx = blockIdx.x * 256 + threadIdx.x;
    if (idx >= N * K) return;
    int n = idx / K;
    int k = idx - n * K;
    Wt[idx] = __float2bfloat16(W[(size_t)k * N + n]);
}

// ---------------------------------------------------------------------------
// MEGA KERNEL: gather + GEMM1 + GEMM2 + head, fully fused.
//   Main loop = R5's proven all-global_load_lds counted-vmcnt pipeline
//   (no NT — R6 showed aux=2 loses A reuse).  Epilogue: h1 never leaves
//   the block — pre-convert acc->bf16, ping-pong 64-col h1 chunks and
//   W2 chunks through freed LDS, MFMA GEMM2, then logits+softmax -> out.
// ---------------------------------------------------------------------------
__global__ __launch_bounds__(512, 2) void mega_k(
    const float* __restrict__ x_raw, const int* __restrict__ x_idx,
    const float* __restrict__ emb, const bf16* __restrict__ W1t,
    const float* __restrict__ b1, const float* __restrict__ S01,
    const bf16* __restrict__ W2t, const float* __restrict__ b2,
    const float* __restrict__ W3, const float* __restrict__ b3,
    float* __restrict__ out)
{
    extern __shared__ char smem[];
    char* Als  = smem;
    char* Bls  = smem + OFF_BLS;
    char* ring = smem + OFF_RING;

    const int tid = threadIdx.x;
    const int w  = tid >> 6, l = tid & 63;
    const int wr = w >> 2, wc = w & 3;          // 2 x 4 wave grid
    const int fr = l & 15, fq = l >> 4;
    const int m0 = blockIdx.x * 160;

    const int arow_sub = l >> 4;                // 0..3   (A: 4 rows/instr)
    const int acol     = l & 15;                // 16B unit within 256B row
    const int brow_sub = l >> 2;                // 0..15  (B: 16 rows/instr)
    const int bcol     = l & 3;                 // 16B unit within 64B row

    f32x4 acc[5][8] = {};

    auto issue_idx = [&](int t, int slot) {     // 1 instr/wave (lanes 0..19)
        if (l < 20)
            gload4((const char*)x_idx + ((size_t)(m0 + w * 20 + l) * T_ + t) * 4,
                   ring + slot * 640 + w * 80);
    };
    auto issue_A = [&](int t, int buf, const int (&iv)[5]) {   // 5 instr/wave
        char* dst = Als + buf * 40960 + (w * 20) * 256;
        #pragma unroll
        for (int p = 0; p < 5; ++p) {
            int row = w * 20 + p * 4 + arow_sub;
            const char* src = (const char*)(emb + ((size_t)t * V_ + (size_t)iv[p]) * D_)
                              + ((acol * 16) ^ ((row & 7) << 4));
            gload16(src, dst + p * 1024);
        }
    };
    auto issue_B = [&](int t, int h) {          // 4 instr/wave
        char* dst = Bls + h * 32768 + w * 4096;
        #pragma unroll
        for (int i = 0; i < 4; ++i) {
            int row = w * 64 + i * 16 + brow_sub;
            const char* src = (const char*)W1t + ((size_t)row * KE + t * 64 + h * 32) * 2
                              + ((bcol * 16) ^ ((row & 3) << 4));
            gload16(src, dst + i * 1024);
        }
    };
    auto read_iv = [&](int slot, int (&iv)[5]) {
        const int* ivp = (const int*)(ring + slot * 640 + w * 80);
        #pragma unroll
        for (int p = 0; p < 5; ++p) iv[p] = ivp[p * 4 + arow_sub];
    };
    auto mfma_half = [&](int abuf, int kk) {
        const char* Ab = Als + abuf * 40960;
        bf16x8 af[5];
        #pragma unroll
        for (int i = 0; i < 5; ++i) {
            int r  = wr * 80 + i * 16 + fr;
            int xr = (r & 7) << 4;
            float4 a0 = *(const float4*)(Ab + r * 256 + ((kk * 128 + fq * 32) ^ xr));
            float4 a1 = *(const float4*)(Ab + r * 256 + ((kk * 128 + fq * 32 + 16) ^ xr));
            bf16x8 t;
            t[0] = (__bf16)a0.x; t[1] = (__bf16)a0.y;
            t[2] = (__bf16)a0.z; t[3] = (__bf16)a0.w;
            t[4] = (__bf16)a1.x; t[5] = (__bf16)a1.y;
            t[6] = (__bf16)a1.z; t[7] = (__bf16)a1.w;
            af[i] = t;
        }
        const char* Bb = Bls + kk * 32768;
        #pragma unroll
        for (int j = 0; j < 8; ++j) {
            int n = wc * 128 + j * 16 + fr;
            bf16x8 bg = *(const bf16x8*)(Bb + n * 64 + ((fq * 16) ^ ((n & 3) << 4)));
            #pragma unroll
            for (int i = 0; i < 5; ++i)
                acc[i][j] = __builtin_amdgcn_mfma_f32_16x16x32_bf16(
                    af[i], bg, acc[i][j], 0, 0, 0);
        }
    };

    // ---- prologue -------------------------------------------------------
    int iv[5];
    issue_idx(0, 0);
    asm volatile("s_waitcnt vmcnt(0)" ::: "memory");
    read_iv(0, iv);
    issue_A(0, 0, iv);                            // +5
    issue_idx(1, 1);                              // +1
    issue_B(0, 0);                                // +4
    issue_B(0, 1);                                // +4   (stack = 14)

    // ---- main loop (R5-proven) -----------------------------------------
    for (int kt = 0; kt < NKT; ++kt) {
        int tA = (kt + 1 < NKT) ? kt + 1 : NKT - 1;
        int t2 = (kt + 2 < NKT) ? kt + 2 : NKT - 1;

        asm volatile("s_waitcnt vmcnt(8)" ::: "memory");   // idx(kt+1), A(kt) done
        read_iv((kt + 1) & 1, iv);
        issue_A(tA, (kt + 1) & 1, iv);                     // +5
        issue_idx(t2, kt & 1);                             // +1
        asm volatile("s_waitcnt vmcnt(10)" ::: "memory");  // B(kt,h0) done
        __builtin_amdgcn_s_barrier();
        __builtin_amdgcn_sched_barrier(0);

        __builtin_amdgcn_s_setprio(1);
        mfma_half(kt & 1, 0);
        __builtin_amdgcn_s_setprio(0);
        asm volatile("s_waitcnt lgkmcnt(0)" ::: "memory");
        __builtin_amdgcn_s_barrier();

        issue_B(tA, 0);                                    // +4
        asm volatile("s_waitcnt vmcnt(10)" ::: "memory");  // B(kt,h1) done
        __builtin_amdgcn_s_barrier();
        __builtin_amdgcn_sched_barrier(0);

        __builtin_amdgcn_s_setprio(1);
        mfma_half(kt & 1, 1);
        __builtin_amdgcn_s_setprio(0);
        asm volatile("s_waitcnt lgkmcnt(0)" ::: "memory");
        __builtin_amdgcn_s_barrier();

        issue_B(tA, 1);                                    // +4
    }
    asm volatile("s_waitcnt vmcnt(0)" ::: "memory");       // drain clamped junk

    // ======================= EPILOGUE: GEMM2 + head ======================
    auto epi_issue = [&](int kc2) {             // W2 chunk kc2 -> Bch[kc2&1]
        char* dst = smem + OFF_BCH + (kc2 & 1) * 32768 + w * 4096;
        #pragma unroll
        for (int q = 0; q < 4; ++q) {
            int row = w * 32 + q * 8 + (l >> 3);
            const char* src = (const char*)W2t + (size_t)row * 1024 + kc2 * 128
                              + (((l & 7) ^ (row & 7)) * 16);
            gload16(src, dst + q * 1024);
        }
    };

    // stage tables into LDS (plain loads; post-drain, outside counted region)
    if (tid < 512) {
        ((float*)(smem + OFF_B1S))[tid] = b1[tid];
        ((float*)(smem + OFF_S0S))[tid] = S01[tid];
        ((float*)(smem + OFF_S1S))[tid] = S01[512 + tid];
    }
    if (tid < 256) {
        ((float*)(smem + OFF_W3S))[tid] = W3[tid];
        ((float*)(smem + OFF_B2S))[tid] = b2[tid];
    }
    if (tid < 160)
        ((float2*)(smem + OFF_XRS))[tid] = ((const float2*)x_raw)[m0 + tid];

    epi_issue(0);
    epi_issue(1);
    __syncthreads();    // tables visible; W2 chunks 0,1 complete (vmcnt drained)

    // pre-convert: h1 = relu(acc + b1 + x0*S0 + x1*S1) -> packed bf16 pairs.
    // h1b[i][j][q] = rows (fq*4+2q, +1), col wc*128+j*16+fr.  Frees acc.
    uint32_t h1b[5][8][2];
    #pragma unroll
    for (int i = 0; i < 5; ++i) {
        int rbase = wr * 80 + i * 16 + fq * 4;
        float4 xa = *(const float4*)(smem + OFF_XRS + rbase * 8);
        float4 xb = *(const float4*)(smem + OFF_XRS + rbase * 8 + 16);
        float x0[4] = {xa.x, xa.z, xb.x, xb.z};
        float x1[4] = {xa.y, xa.w, xb.y, xb.w};
        #pragma unroll
        for (int j = 0; j < 8; ++j) {
            int n = wc * 128 + j * 16 + fr;
            float bb = *(const float*)(smem + OFF_B1S + n * 4);
            float s0 = *(const float*)(smem + OFF_S0S + n * 4);
            float s1 = *(const float*)(smem + OFF_S1S + n * 4);
            #pragma unroll
            for (int q = 0; q < 2; ++q) {
                float v0 = fmaxf(acc[i][j][2*q]   + bb + x0[2*q]*s0   + x1[2*q]*s1,   0.f);
                float v1 = fmaxf(acc[i][j][2*q+1] + bb + x0[2*q+1]*s0 + x1[2*q+1]*s1, 0.f);
                h1b[i][j][q] = (uint32_t)b16bits(v0) | ((uint32_t)b16bits(v1) << 16);
            }
        }
    }

    f32x4 acc2[5][4] = {};

    auto epi_write = [&](int kc) {              // owner waves write h1 chunk
        if (wc == (kc >> 1)) {
            char* Ach = smem + OFF_ACH + (kc & 1) * 20480;
            #pragma unroll
            for (int i = 0; i < 5; ++i) {
                #pragma unroll
                for (int jj = 0; jj < 4; ++jj) {
                    int j = (kc & 1) * 4 + jj;
                    #pragma unroll
                    for (int q = 0; q < 2; ++q) {
                        uint32_t p2 = h1b[i][j][q];
                        int rw0 = wr * 80 + i * 16 + fq * 4 + 2 * q;
                        int cb  = (jj * 16 + fr) * 2;
                        *(uint16_t*)(Ach + ((rw0 * 128 + cb) ^ ((rw0 & 7) << 4)))
                            = (uint16_t)p2;
                        int rw1 = rw0 + 1;
                        *(uint16_t*)(Ach + ((rw1 * 128 + cb) ^ ((rw1 & 7) << 4)))
                            = (uint16_t)(p2 >> 16);
                    }
                }
            }
        }
    };
    auto epi_mfma = [&](int kc) {
        const char* Ach = smem + OFF_ACH + (kc & 1) * 20480;
        const char* Bch = smem + OFF_BCH + (kc & 1) * 32768;
        #pragma unroll
        for (int kk = 0; kk < 2; ++kk) {
            bf16x8 af[5];
            #pragma unroll
            for (int i = 0; i < 5; ++i) {
                int r = wr * 80 + i * 16 + fr;
                af[i] = *(const bf16x8*)(Ach + ((r * 128 + kk * 64 + fq * 16)
                                                ^ ((r & 7) << 4)));
            }
            #pragma unroll
            for (int j2 = 0; j2 < 4; ++j2) {
                int n2 = wc * 64 + j2 * 16 + fr;
                bf16x8 bg = *(const bf16x8*)(Bch + ((n2 * 128 + kk * 64 + fq * 16)
                                                    ^ ((n2 & 7) << 4)));
                #pragma unroll
                for (int i = 0; i < 5; ++i)
                    acc2[i][j2] = __builtin_amdgcn_mfma_f32_16x16x32_bf16(
                        af[i], bg, acc2[i][j2], 0, 0, 0);
            }
        }
    };

    // kc = 0
    epi_write(0);
    asm volatile("s_waitcnt lgkmcnt(0)" ::: "memory");
    __builtin_amdgcn_s_barrier();
    epi_mfma(0);
    asm volatile("s_waitcnt lgkmcnt(0)" ::: "memory");
    __builtin_amdgcn_s_barrier();
    epi_issue(2);
    // kc = 1
    epi_write(1);
    asm volatile("s_waitcnt lgkmcnt(0)" ::: "memory");
    __builtin_amdgcn_s_barrier();
    epi_mfma(1);
    asm volatile("s_waitcnt lgkmcnt(0)" ::: "memory");
    __builtin_amdgcn_s_barrier();
    epi_issue(3);
    // kc = 2..6 steady: wait vmcnt(4) for chunk kc, prefetch kc+2
    #pragma unroll
    for (int kc = 2; kc <= 6; ++kc) {
        epi_write(kc);
        asm volatile("s_waitcnt lgkmcnt(0)" ::: "memory");
        asm volatile("s_waitcnt vmcnt(4)" ::: "memory");
        __builtin_amdgcn_s_barrier();
        epi_mfma(kc);
        asm volatile("s_waitcnt lgkmcnt(0)" ::: "memory");
        __builtin_amdgcn_s_barrier();
        if (kc + 2 <= 7) epi_issue(kc + 2);
    }
    // kc = 7
    epi_write(7);
    asm volatile("s_waitcnt lgkmcnt(0)" ::: "memory");
    asm volatile("s_waitcnt vmcnt(0)" ::: "memory");
    __builtin_amdgcn_s_barrier();
    epi_mfma(7);
    asm volatile("s_waitcnt lgkmcnt(0)" ::: "memory");
    __builtin_amdgcn_s_barrier();

    // ---- head: logits + softmax ----------------------------------------
    float* logq   = (float*)(smem + OFF_LOGQ);   // [4][160]
    float* logits = (float*)(smem + OFF_LOG);    // [160]
    #pragma unroll
    for (int i = 0; i < 5; ++i) {
        #pragma unroll
        for (int r2 = 0; r2 < 4; ++r2) {
            float s = 0.f;
            #pragma unroll
            for (int j2 = 0; j2 < 4; ++j2) {
                int n2 = wc * 64 + j2 * 16 + fr;
                float v = fmaxf(acc2[i][j2][r2]
                                + *(const float*)(smem + OFF_B2S + n2 * 4), 0.f);
                s += v * *(const float*)(smem + OFF_W3S + n2 * 4);
            }
            #pragma unroll
            for (int off = 1; off < 16; off <<= 1) s += __shfl_xor(s, off);
            if (fr == 0)
                logq[wc * 160 + wr * 80 + i * 16 + fq * 4 + r2] = s;
        }
    }
    __syncthreads();
    if (tid < 160)
        logits[tid] = logq[tid] + logq[160 + tid] + logq[320 + tid]
                    + logq[480 + tid] + b3[0];
    __syncthreads();
    if (tid < 160) {
        int bb = (tid / 20) * 20;
        float mx = -1e30f;
        #pragma unroll
        for (int p = 0; p < 20; ++p) mx = fmaxf(mx, logits[bb + p]);
        float sum = 0.f;
        #pragma unroll
        for (int p = 0; p < 20; ++p) sum += expf(logits[bb + p] - mx);
        out[m0 + tid] = expf(logits[tid] - mx) / sum;
    }
}

// ---------------------------------------------------------------------------
extern "C" void kernel_launch(void* const* d_in, const int* in_sizes, int n_in,
                              void* d_out, int out_size, void* d_ws, size_t ws_size,
                              hipStream_t stream)
{
    const float* x_raw = (const float*)d_in[0];
    const int*   x_idx = (const int*)  d_in[1];
    const float* emb   = (const float*)d_in[2];
    const float* W1    = (const float*)d_in[3];
    const float* b1    = (const float*)d_in[4];
    const float* W2    = (const float*)d_in[5];
    const float* b2    = (const float*)d_in[6];
    const float* W3    = (const float*)d_in[7];
    const float* b3    = (const float*)d_in[8];

    char* ws = (char*)d_ws;
    size_t off = 0;
    bf16*  W1t = (bf16*) (ws + off); off += (size_t)H1_ * KE * 2;    // 2.16 MB
    bf16*  W2t = (bf16*) (ws + off); off += (size_t)H2_ * H1_ * 2;   // 0.26 MB
    float* S01 = (float*)(ws + off); off += (size_t)2 * H1_ * 4;     // 4 KB

    // prep
    colsum_k<<<4, 256, 0, stream>>>(W1, S01);
    w1t_k<<<(H1_ * KE) / 256, 256, 0, stream>>>(W1, W1t);
    transpose_bf16_k<<<(H2_ * H1_ + 255) / 256, 256, 0, stream>>>(W2, W2t, H1_, H2_);

    // mega kernel: gather + GEMM1 + GEMM2 + head
    hipFuncSetAttribute((const void*)mega_k,
                        hipFuncAttributeMaxDynamicSharedMemorySize, LDS_BYTES);
    mega_k<<<256, 512, LDS_BYTES, stream>>>(x_raw, x_idx, emb, W1t, b1, S01,
                                            W2t, b2, W3, b3, (float*)d_out);
}